// Round 6
// baseline (5332.466 us; speedup 1.0000x reference)
//
#include <hip/hip_runtime.h>

#define EPS 1e-5f
#define SLOPE 0.01f

typedef __attribute__((ext_vector_type(8))) short bf16x8;
typedef __attribute__((ext_vector_type(4))) float f32x4;

static __device__ __forceinline__ unsigned short f2bf(float f) {
    unsigned u = __float_as_uint(f);
    u += 0x7fff + ((u >> 16) & 1);          // round-to-nearest-even
    return (unsigned short)(u >> 16);
}
static __device__ __forceinline__ float bf2f(unsigned short h) {
    return __uint_as_float(((unsigned)h) << 16);
}

// ---------------------------------------------------------------------------
// Gather-GEMM submanifold conv, bf16 MFMA 16x16x32.
// DECOUPLED structure (AITER-style, barrier-free): gathers are consumed by
// ds_write into a PER-WAVE-PRIVATE LDS buffer (auto-waitcnt is fine-grained
// vmcnt(N) for vmem->ds_write chains); MFMAs consume ds_read fragments
// (lgkmcnt only). No __syncthreads in the k-loop -> no vmcnt(0) drain.
// Gathers issue 2 chunks ahead (3 sub-phases of slack); B prefetches 1
// sub-phase ahead. LDS atoms XOR-swizzled: atom (row r, seg s) at
// (r*8 + (s^(r&7)))*16B -> bank-optimal for b128 write and frag read.
// Chunk = 64 input channels of one k-offset (NCH chunks per k).
// Sub-phase = 32 channels (one MFMA K-step): 8 MFMAs each.
template<int K, int NCH>
__global__ __launch_bounds__(256, 3)
void conv_mfma(const unsigned short* __restrict__ in, int tableN,
               const int* __restrict__ nbr, int Nout,
               const unsigned short* __restrict__ Wt,   // [K][64][Cin] bf16
               const float* __restrict__ skip,
               unsigned short* __restrict__ out_bf,
               float* __restrict__ out_f32,
               float* __restrict__ stats, int do_lrelu)
{
    constexpr int Cin = NCH * 64;
    constexpr int KT  = K * NCH;            // 64-channel chunks
    static_assert(KT >= 3, "pipeline depth");

    __shared__ unsigned short Abuf[4][2][2048];   // [wave][buf][32r*8s*8ch] 4KB each
    __shared__ int   sIdx[K][128];
    __shared__ float red[2][64][4];

    const int t    = threadIdx.x;
    const int lane = t & 63;
    const int w    = t >> 6;
    const int q    = lane >> 4;             // quad 0..3
    const int m    = lane & 15;
    const int row0 = blockIdx.x * 128;
    const int wrow = w * 32;                // this wave's rows within block

    // gather lane mapping (constants per lane)
    const int gbr = lane >> 3;              // base row 0..7 (+8j)
    const int gs  = lane & 7;               // 16B segment 0..7
    const int gsw = gs ^ gbr;               // swizzled segment for ds_write

    // ---- stage all K x 128 indices into LDS (coalesced), one barrier
    for (int e = t; e < K * 128; e += 256) {
        int k = e >> 7, r = e & 127;
        int gr = row0 + r;
        sIdx[k][r] = (gr < Nout) ? nbr[(size_t)k * Nout + gr] : tableN;
    }
    __syncthreads();

    f32x4 acc[2][4];
#pragma unroll
    for (int rt = 0; rt < 2; ++rt)
#pragma unroll
        for (int ct = 0; ct < 4; ++ct) acc[rt][ct] = (f32x4){0.f, 0.f, 0.f, 0.f};

    bf16x8 g[2][4];                         // gather generations (2 chunks deep)
    bf16x8 bE[4], bO[4];                    // B-frags: even (kc=0) / odd (kc=1)

    // gather chunk -> 4 x 16B per lane (rows gbr+8j, segment gs)
    auto gather = [&](int chunk, bf16x8 (&gg)[4]) {
        const int k  = chunk / NCH;
        const int cc = chunk % NCH;
#pragma unroll
        for (int j = 0; j < 4; ++j) {
            int src = sIdx[k][wrow + gbr + 8 * j];
            gg[j] = *(const bf16x8*)(in + (size_t)src * Cin + cc * 64 + gs * 8);
        }
    };
    // ds_write gathered chunk into private buf p (swizzled)
    auto dswrite = [&](int p, const bf16x8 (&gg)[4]) {
        unsigned short* base = &Abuf[w][p][0];
#pragma unroll
        for (int j = 0; j < 4; ++j)
            *(bf16x8*)(base + (gbr + 8 * j) * 64 + gsw * 8) = gg[j];
    };
    // read A fragment: rows rt*16+m, channels kc*32 + q*8 + [0..7]
    auto dsreadA = [&](int p, int rt, int kc) -> bf16x8 {
        int r  = rt * 16 + m;
        int ss = (kc * 4 + q) ^ (m & 7);
        return *(const bf16x8*)(&Abuf[w][p][r * 64 + ss * 8]);
    };
    // B fragment: lane(q,m), ct: d = ct*16+m, c = kc*32 + q*8
    auto loadB = [&](int chunk, int kc, bf16x8 (&bb)[4]) {
        const int k  = chunk / NCH;
        const int cc = chunk % NCH;
        const unsigned short* p =
            Wt + ((size_t)k * 64 + m) * Cin + cc * 64 + kc * 32 + q * 8;
#pragma unroll
        for (int ct = 0; ct < 4; ++ct)
            bb[ct] = *(const bf16x8*)(p + (size_t)ct * 16 * Cin);
    };

    // ---- prologue: chunk 0 into buf0 (one cold stall), chunk 1 in flight
    gather(0, g[0]);
    dswrite(0, g[0]);
    gather(1, g[1]);
    loadB(0, 0, bE);

#pragma unroll
    for (int kk = 0; kk < KT; ++kk) {
        const int p = kk & 1;
        // ---- sub-phase A (kc=0): uses bE, prefetches gather(kk+2) & B(kk,1)
        if (kk + 2 < KT) gather(kk + 2, g[p]);   // g[p]'s old content already in LDS
        loadB(kk, 1, bO);
        {
            bf16x8 a0 = dsreadA(p, 0, 0);
            bf16x8 a1 = dsreadA(p, 1, 0);
#pragma unroll
            for (int ct = 0; ct < 4; ++ct) {
                acc[0][ct] = __builtin_amdgcn_mfma_f32_16x16x32_bf16(a0, bE[ct], acc[0][ct], 0, 0, 0);
                acc[1][ct] = __builtin_amdgcn_mfma_f32_16x16x32_bf16(a1, bE[ct], acc[1][ct], 0, 0, 0);
            }
        }
        // ---- sub-phase B (kc=1): uses bO, commits gather(kk+1), prefetches B(kk+1,0)
        if (kk + 1 < KT) dswrite(p ^ 1, g[p ^ 1]);   // auto vmcnt(N) waits only these
        if (kk + 1 < KT) loadB(kk + 1, 0, bE);
        {
            bf16x8 a0 = dsreadA(p, 0, 1);
            bf16x8 a1 = dsreadA(p, 1, 1);
#pragma unroll
            for (int ct = 0; ct < 4; ++ct) {
                acc[0][ct] = __builtin_amdgcn_mfma_f32_16x16x32_bf16(a0, bO[ct], acc[0][ct], 0, 0, 0);
                acc[1][ct] = __builtin_amdgcn_mfma_f32_16x16x32_bf16(a1, bO[ct], acc[1][ct], 0, 0, 0);
            }
        }
    }

    // ---- epilogue: C/D layout col=lane&15 (n), row=q*4+reg (verified m89/m91)
    float psum[4] = {0.f, 0.f, 0.f, 0.f}, psq[4] = {0.f, 0.f, 0.f, 0.f};
#pragma unroll
    for (int rt = 0; rt < 2; ++rt) {
#pragma unroll
        for (int ct = 0; ct < 4; ++ct) {
            int col = ct * 16 + m;
#pragma unroll
            for (int reg = 0; reg < 4; ++reg) {
                int r = row0 + wrow + rt * 16 + q * 4 + reg;
                if (r < Nout) {
                    float v = acc[rt][ct][reg];
                    if (skip) v += skip[(size_t)r * 64 + col];
                    if (do_lrelu) v = (v >= 0.f) ? v : SLOPE * v;
                    if (out_bf) out_bf[(size_t)r * 64 + col] = f2bf(v);
                    else        out_f32[(size_t)r * 64 + col] = v;
                    psum[ct] += v;
                    psq[ct]  += v * v;
                }
            }
        }
    }

    if (stats) {
        // lanes m, m+16, m+32, m+48 share channel -> shuffle-reduce to q==0
#pragma unroll
        for (int ct = 0; ct < 4; ++ct) {
            psum[ct] += __shfl_down(psum[ct], 32);
            psum[ct] += __shfl_down(psum[ct], 16);
            psq[ct]  += __shfl_down(psq[ct], 32);
            psq[ct]  += __shfl_down(psq[ct], 16);
        }
        if (q == 0) {
#pragma unroll
            for (int ct = 0; ct < 4; ++ct) {
                red[0][ct * 16 + m][w] = psum[ct];
                red[1][ct * 16 + m][w] = psq[ct];
            }
        }
        __syncthreads();
        if (t < 64) {
            float s  = red[0][t][0] + red[0][t][1] + red[0][t][2] + red[0][t][3];
            float qq = red[1][t][0] + red[1][t][1] + red[1][t][2] + red[1][t][3];
            atomicAdd(&stats[t], s);
            atomicAdd(&stats[64 + t], qq);
        }
    }
}

// BN apply on bf16 buffer in-place.
__global__ __launch_bounds__(256)
void bn_apply_bf16(unsigned short* __restrict__ buf, size_t total8,
                   const float* __restrict__ stats,
                   const float* __restrict__ gamma,
                   const float* __restrict__ beta, float invN)
{
    __shared__ float sc[64], sh[64];
    int t = threadIdx.x;
    if (t < 64) {
        float mean = stats[t] * invN;
        float var  = stats[64 + t] * invN - mean * mean;
        float s    = gamma[t] * rsqrtf(var + EPS);
        sc[t] = s;
        sh[t] = beta[t] - mean * s;
    }
    __syncthreads();
    for (size_t i = (size_t)blockIdx.x * blockDim.x + t; i < total8;
         i += (size_t)gridDim.x * blockDim.x) {
        int4 v = ((const int4*)buf)[i];
        unsigned short* e = (unsigned short*)&v;
        int c0 = ((int)(i & 7)) << 3;
#pragma unroll
        for (int j = 0; j < 8; ++j)
            e[j] = f2bf(bf2f(e[j]) * sc[c0 + j] + sh[c0 + j]);
        ((int4*)buf)[i] = v;
    }
}

// BN apply fp32 in-place (final layer -> d_out).
__global__ __launch_bounds__(256)
void bn_apply_f32(float* __restrict__ buf, int N,
                  const float* __restrict__ stats,
                  const float* __restrict__ gamma,
                  const float* __restrict__ beta, float invN)
{
    __shared__ float sc[64], sh[64];
    int t = threadIdx.x;
    if (t < 64) {
        float mean = stats[t] * invN;
        float var  = stats[64 + t] * invN - mean * mean;
        float s    = gamma[t] * rsqrtf(var + EPS);
        sc[t] = s;
        sh[t] = beta[t] - mean * s;
    }
    __syncthreads();
    size_t total4 = (size_t)N * 16;
    for (size_t i = (size_t)blockIdx.x * blockDim.x + t; i < total4;
         i += (size_t)gridDim.x * blockDim.x) {
        float4 v = ((const float4*)buf)[i];
        int c0 = ((int)(i & 15)) << 2;
        v.x = v.x * sc[c0]     + sh[c0];
        v.y = v.y * sc[c0 + 1] + sh[c0 + 1];
        v.z = v.z * sc[c0 + 2] + sh[c0 + 2];
        v.w = v.w * sc[c0 + 3] + sh[c0 + 3];
        ((float4*)buf)[i] = v;
    }
}

// fp32 -> bf16 elementwise convert (x_feats).
__global__ __launch_bounds__(256)
void cvt_bf16(const float* __restrict__ in, unsigned short* __restrict__ out,
              size_t n4)
{
    for (size_t i = (size_t)blockIdx.x * blockDim.x + threadIdx.x; i < n4;
         i += (size_t)gridDim.x * blockDim.x) {
        float4 v = ((const float4*)in)[i];
        ushort4 o;
        o.x = f2bf(v.x); o.y = f2bf(v.y); o.z = f2bf(v.z); o.w = f2bf(v.w);
        ((ushort4*)out)[i] = o;
    }
}

// Zero the sentinel rows (index tableN) of all gatherable feature tables.
__global__ __launch_bounds__(256)
void zero_sentinels(unsigned short* xb, int Nin128,
                    unsigned short* tb, int Nin64,
                    unsigned short* ub, unsigned short* ab, unsigned short* vb,
                    int Nout64)
{
    int t = threadIdx.x;
    if (t < 128) xb[(size_t)Nin128 + t] = 0;
    if (t < 64) {
        tb[(size_t)Nin64 + t] = 0;
        ub[(size_t)Nout64 + t] = 0;
        ab[(size_t)Nout64 + t] = 0;
        vb[(size_t)Nout64 + t] = 0;
    }
}

static __device__ __forceinline__ void wt_one(int e, const float* __restrict__ W,
                                              unsigned short* __restrict__ Wt,
                                              int Cin)
{
    // e indexes Wt flat [k][d][c]
    int c = e % Cin;
    int rest = e / Cin;
    int d = rest & 63;
    int k = rest >> 6;
    Wt[e] = f2bf(W[((size_t)k * Cin + c) * 64 + d]);
}

// All 5 weight transposes ([K][Cin][64] f32 -> [K][64][Cin] bf16) in one launch.
__global__ __launch_bounds__(256)
void wt_cvt_all(const float* __restrict__ W_trans, const float* __restrict__ W_up,
                const float* __restrict__ W1, const float* __restrict__ W2,
                const float* __restrict__ W3,
                unsigned short* __restrict__ wt_t, unsigned short* __restrict__ wt_u,
                unsigned short* __restrict__ wt1, unsigned short* __restrict__ wt2,
                unsigned short* __restrict__ wt3)
{
    const int S0 = 27 * 128 * 64;            // trans
    const int S1 = 27 * 64 * 64;             // up
    const int S2 = 9 * 64 * 64;              // W1
    const int S3 = 9 * 64 * 64;              // W2
    const int S4 = 27 * 64 * 64;             // W3
    int e = blockIdx.x * blockDim.x + threadIdx.x;
    if (e < S0) { wt_one(e, W_trans, wt_t, 128); return; }
    e -= S0;
    if (e < S1) { wt_one(e, W_up, wt_u, 64); return; }
    e -= S1;
    if (e < S2) { wt_one(e, W1, wt1, 64); return; }
    e -= S2;
    if (e < S3) { wt_one(e, W2, wt2, 64); return; }
    e -= S3;
    if (e < S4) { wt_one(e, W3, wt3, 64); }
}

extern "C" void kernel_launch(void* const* d_in, const int* in_sizes, int n_in,
                              void* d_out, int out_size, void* d_ws, size_t ws_size,
                              hipStream_t stream) {
    const float* x_feats   = (const float*)d_in[0];
    const float* skip      = (const float*)d_in[1];
    const int*   nbr_trans = (const int*)d_in[2];
    const int*   nbr_up    = (const int*)d_in[3];
    const int*   nbr1      = (const int*)d_in[4];
    const int*   nbr2      = (const int*)d_in[5];
    const int*   nbr3      = (const int*)d_in[6];
    const float* W_trans   = (const float*)d_in[7];
    const float* W_up      = (const float*)d_in[8];
    const float* W1        = (const float*)d_in[9];
    const float* W2        = (const float*)d_in[10];
    const float* W3        = (const float*)d_in[11];
    const float* gamma_t   = (const float*)d_in[12];
    const float* beta_t    = (const float*)d_in[13];
    const float* gamma1    = (const float*)d_in[14];
    const float* beta1     = (const float*)d_in[15];
    const float* gamma2    = (const float*)d_in[16];
    const float* beta2     = (const float*)d_in[17];
    const float* gamma3    = (const float*)d_in[18];
    const float* beta3     = (const float*)d_in[19];

    const int Nin  = in_sizes[0] / 128;   // 80000
    const int Nout = in_sizes[1] / 64;    // 200000

    // ---- workspace layout. Each feature table has one extra (sentinel) row,
    // zeroed every launch.
    size_t off = 0;
    auto alloc = [&](size_t bytes) {
        void* p = (char*)d_ws + off;
        off = (off + bytes + 255) & ~(size_t)255;
        return p;
    };
    unsigned short* xb   = (unsigned short*)alloc(((size_t)Nin + 1) * 128 * 2);
    unsigned short* tb   = (unsigned short*)alloc(((size_t)Nin + 1) * 64 * 2);
    unsigned short* ub   = (unsigned short*)alloc(((size_t)Nout + 1) * 64 * 2);
    unsigned short* ab   = (unsigned short*)alloc(((size_t)Nout + 1) * 64 * 2);
    unsigned short* vb   = (unsigned short*)alloc(((size_t)Nout + 1) * 64 * 2);
    unsigned short* wt_t = (unsigned short*)alloc((size_t)27 * 128 * 64 * 2);
    unsigned short* wt_u = (unsigned short*)alloc((size_t)27 * 64 * 64 * 2);
    unsigned short* wt1  = (unsigned short*)alloc((size_t)9 * 64 * 64 * 2);
    unsigned short* wt2  = (unsigned short*)alloc((size_t)9 * 64 * 64 * 2);
    unsigned short* wt3  = (unsigned short*)alloc((size_t)27 * 64 * 64 * 2);
    float* stats = (float*)alloc(512 * sizeof(float));
    float* out   = (float*)d_out;

    hipMemsetAsync(stats, 0, 512 * sizeof(float), stream);

    dim3 blk(256);
    const float invNin  = 1.f / (float)Nin;
    const float invNout = 1.f / (float)Nout;

    wt_cvt_all<<<2016, blk, 0, stream>>>(W_trans, W_up, W1, W2, W3,
                                         wt_t, wt_u, wt1, wt2, wt3);
    cvt_bf16<<<2048, blk, 0, stream>>>(x_feats, xb, (size_t)Nin * 32);
    zero_sentinels<<<1, blk, 0, stream>>>(xb, Nin * 128, tb, Nin * 64,
                                          ub, ab, vb, Nout * 64);

    const int gIn  = (Nin  + 127) / 128;  // 625
    const int gOut = (Nout + 127) / 128;  // 1563

    // trans_dilao: Cin=128, K=27 + LeakyReLU + BN
    conv_mfma<27, 2><<<gIn, blk, 0, stream>>>(xb, Nin, nbr_trans, Nin,
                                              wt_t, nullptr, tb, nullptr, stats + 0, 1);
    bn_apply_bf16<<<1024, blk, 0, stream>>>(tb, (size_t)Nin * 8, stats + 0,
                                            gamma_t, beta_t, invNin);
    // SparseInverseConv K=27 + skip (no act/bn)
    conv_mfma<27, 1><<<gOut, blk, 0, stream>>>(tb, Nin, nbr_up, Nout,
                                               wt_u, skip, ub, nullptr, nullptr, 0);
    // conv1 K=9 + LeakyReLU + BN
    conv_mfma<9, 1><<<gOut, blk, 0, stream>>>(ub, Nout, nbr1, Nout,
                                              wt1, nullptr, ab, nullptr, stats + 128, 1);
    bn_apply_bf16<<<2048, blk, 0, stream>>>(ab, (size_t)Nout * 8, stats + 128,
                                            gamma1, beta1, invNout);
    // conv2 K=9 + LeakyReLU + BN
    conv_mfma<9, 1><<<gOut, blk, 0, stream>>>(ab, Nout, nbr2, Nout,
                                              wt2, nullptr, vb, nullptr, stats + 256, 1);
    bn_apply_bf16<<<2048, blk, 0, stream>>>(vb, (size_t)Nout * 8, stats + 256,
                                            gamma2, beta2, invNout);
    // conv3 K=27 + LeakyReLU + BN -> d_out (fp32), normalize in place
    conv_mfma<27, 1><<<gOut, blk, 0, stream>>>(vb, Nout, nbr3, Nout,
                                               wt3, nullptr, nullptr, out, stats + 384, 1);
    bn_apply_f32<<<2048, blk, 0, stream>>>(out, Nout, stats + 384,
                                           gamma3, beta3, invNout);
}

// Round 7
// 724.514 us; speedup vs baseline: 7.3601x; 7.3601x over previous
//
#include <hip/hip_runtime.h>

#define EPS 1e-5f
#define SLOPE 0.01f

typedef __attribute__((ext_vector_type(8))) short bf16x8;
typedef __attribute__((ext_vector_type(4))) float f32x4;

static __device__ __forceinline__ unsigned short f2bf(float f) {
    unsigned u = __float_as_uint(f);
    u += 0x7fff + ((u >> 16) & 1);          // round-to-nearest-even
    return (unsigned short)(u >> 16);
}
static __device__ __forceinline__ float bf2f(unsigned short h) {
    return __uint_as_float(((unsigned)h) << 16);
}

// async 16B global -> LDS (DMA, no VGPR round-trip). LDS dest = base + lane*16.
static __device__ __forceinline__ void gload16(const unsigned short* g, void* l) {
    __builtin_amdgcn_global_load_lds(
        (const __attribute__((address_space(1))) unsigned int*)g,
        (__attribute__((address_space(3))) unsigned int*)l,
        16, 0, 0);
}

// ---------------------------------------------------------------------------
// Gather-GEMM submanifold conv, bf16 MFMA 16x16x32, m97-style structure:
// double-buffered LDS A-tile filled by global_load_lds (per-lane gather
// addresses, lane-contiguous LDS dest), one __syncthreads per 64-channel
// chunk (its vmcnt(0) drain covers loads issued a full compute phase ago).
// Each wave owns 32 rows x 64 cols; no cross-wave LDS sharing.
// B-fragments: fully coalesced 1KB loads from pre-permuted weights
// Wt2[kk][kc][ct][lane][8], double-buffered in registers.
// Feature tables carry a zeroed sentinel row at index tableN.
template<int K, int NCH>
__global__ __launch_bounds__(256, 3)
void conv_mfma(const unsigned short* __restrict__ in, int tableN,
               const int* __restrict__ nbr, int Nout,
               const unsigned short* __restrict__ Wt2,  // [K*NCH][2][4][64][8] bf16
               const float* __restrict__ skip,
               unsigned short* __restrict__ out_bf,
               float* __restrict__ out_f32,
               float* __restrict__ stats, int do_lrelu)
{
    constexpr int Cin = NCH * 64;
    constexpr int KT  = K * NCH;              // 64-channel chunks

    __shared__ unsigned short Abuf[2][128 * 64];   // 2 x 16KB, rows of 128B
    __shared__ int   sIdx[K * 128];
    __shared__ float red[2][64][4];

    const int t    = threadIdx.x;
    const int lane = t & 63;
    const int w    = t >> 6;
    const int q    = lane >> 4;               // quad 0..3
    const int m    = lane & 15;
    const int row0 = blockIdx.x * 128;
    const int wrow = w * 32;                  // this wave's 32 rows

    const int glr = lane >> 3;                // gather: row-in-group 0..7
    const int gls = lane & 7;                 // gather: 16B segment 0..7

    // ---- stage all K x 128 indices (coalesced), one barrier
    for (int e = t; e < K * 128; e += 256) {
        int k = e >> 7, r = e & 127;
        int gr = row0 + r;
        sIdx[e] = (gr < Nout) ? nbr[(size_t)k * Nout + gr] : tableN;
    }
    __syncthreads();

    f32x4 acc[2][4];
#pragma unroll
    for (int rt = 0; rt < 2; ++rt)
#pragma unroll
        for (int ct = 0; ct < 4; ++ct) acc[rt][ct] = (f32x4){0.f, 0.f, 0.f, 0.f};

    // issue this wave's 4 DMA gathers for chunk kk into buf p
    auto gather = [&](int kk, int p) {
        const int k  = kk / NCH;
        const int cc = kk % NCH;
        const int* sI = &sIdx[k * 128 + wrow];
#pragma unroll
        for (int j = 0; j < 4; ++j) {
            int src = sI[j * 8 + glr];
            const unsigned short* g =
                in + (size_t)src * Cin + cc * 64 + gls * 8;
            gload16(g, (void*)&Abuf[p][(wrow + j * 8) * 64]);  // wave-uniform base
        }
    };
    // coalesced B-fragment load: 8 x 1KB, L2-resident
    auto loadB = [&](int kk, bf16x8 (&bb)[2][4]) {
#pragma unroll
        for (int kc = 0; kc < 2; ++kc)
#pragma unroll
            for (int ct = 0; ct < 4; ++ct)
                bb[kc][ct] = *(const bf16x8*)(
                    Wt2 + (((size_t)(kk * 2 + kc) * 4 + ct) * 64 + lane) * 8);
    };

    bf16x8 bR[2][2][4];                       // [buf][kc][ct]
    gather(0, 0);
    loadB(0, bR[0]);
    __syncthreads();                          // drains chunk-0 DMA

#pragma unroll
    for (int kk = 0; kk < KT; ++kk) {
        const int p = kk & 1;
        if (kk + 1 < KT) {
            gather(kk + 1, p ^ 1);            // in flight through this compute phase
            loadB(kk + 1, bR[p ^ 1]);
        }
        bf16x8 a[2][2];
#pragma unroll
        for (int kc = 0; kc < 2; ++kc)
#pragma unroll
            for (int rt = 0; rt < 2; ++rt)
                a[kc][rt] = *(const bf16x8*)
                    &Abuf[p][(wrow + rt * 16 + m) * 64 + (kc * 4 + q) * 8];
#pragma unroll
        for (int kc = 0; kc < 2; ++kc)
#pragma unroll
            for (int rt = 0; rt < 2; ++rt)
#pragma unroll
                for (int ct = 0; ct < 4; ++ct)
                    acc[rt][ct] = __builtin_amdgcn_mfma_f32_16x16x32_bf16(
                        a[kc][rt], bR[p][kc][ct], acc[rt][ct], 0, 0, 0);
        __syncthreads();                      // vmcnt(0): kk+1 DMA landed; buf p reusable
    }

    // ---- epilogue: C/D layout col=lane&15 (n), row=q*4+reg (verified m89/m91)
    float psum[4] = {0.f, 0.f, 0.f, 0.f}, psq[4] = {0.f, 0.f, 0.f, 0.f};
#pragma unroll
    for (int rt = 0; rt < 2; ++rt) {
#pragma unroll
        for (int ct = 0; ct < 4; ++ct) {
            int col = ct * 16 + m;
#pragma unroll
            for (int reg = 0; reg < 4; ++reg) {
                int r = row0 + wrow + rt * 16 + q * 4 + reg;
                if (r < Nout) {
                    float v = acc[rt][ct][reg];
                    if (skip) v += skip[(size_t)r * 64 + col];
                    if (do_lrelu) v = (v >= 0.f) ? v : SLOPE * v;
                    if (out_bf) out_bf[(size_t)r * 64 + col] = f2bf(v);
                    else        out_f32[(size_t)r * 64 + col] = v;
                    psum[ct] += v;
                    psq[ct]  += v * v;
                }
            }
        }
    }

    if (stats) {
#pragma unroll
        for (int ct = 0; ct < 4; ++ct) {
            psum[ct] += __shfl_down(psum[ct], 32);
            psum[ct] += __shfl_down(psum[ct], 16);
            psq[ct]  += __shfl_down(psq[ct], 32);
            psq[ct]  += __shfl_down(psq[ct], 16);
        }
        if (q == 0) {
#pragma unroll
            for (int ct = 0; ct < 4; ++ct) {
                red[0][ct * 16 + m][w] = psum[ct];
                red[1][ct * 16 + m][w] = psq[ct];
            }
        }
        __syncthreads();
        if (t < 64) {
            float s  = red[0][t][0] + red[0][t][1] + red[0][t][2] + red[0][t][3];
            float qq = red[1][t][0] + red[1][t][1] + red[1][t][2] + red[1][t][3];
            atomicAdd(&stats[t], s);
            atomicAdd(&stats[64 + t], qq);
        }
    }
}

// BN apply on bf16 buffer in-place.
__global__ __launch_bounds__(256)
void bn_apply_bf16(unsigned short* __restrict__ buf, size_t total8,
                   const float* __restrict__ stats,
                   const float* __restrict__ gamma,
                   const float* __restrict__ beta, float invN)
{
    __shared__ float sc[64], sh[64];
    int t = threadIdx.x;
    if (t < 64) {
        float mean = stats[t] * invN;
        float var  = stats[64 + t] * invN - mean * mean;
        float s    = gamma[t] * rsqrtf(var + EPS);
        sc[t] = s;
        sh[t] = beta[t] - mean * s;
    }
    __syncthreads();
    for (size_t i = (size_t)blockIdx.x * blockDim.x + t; i < total8;
         i += (size_t)gridDim.x * blockDim.x) {
        int4 v = ((const int4*)buf)[i];
        unsigned short* e = (unsigned short*)&v;
        int c0 = ((int)(i & 7)) << 3;
#pragma unroll
        for (int j = 0; j < 8; ++j)
            e[j] = f2bf(bf2f(e[j]) * sc[c0 + j] + sh[c0 + j]);
        ((int4*)buf)[i] = v;
    }
}

// BN apply fp32 in-place (final layer -> d_out).
__global__ __launch_bounds__(256)
void bn_apply_f32(float* __restrict__ buf, int N,
                  const float* __restrict__ stats,
                  const float* __restrict__ gamma,
                  const float* __restrict__ beta, float invN)
{
    __shared__ float sc[64], sh[64];
    int t = threadIdx.x;
    if (t < 64) {
        float mean = stats[t] * invN;
        float var  = stats[64 + t] * invN - mean * mean;
        float s    = gamma[t] * rsqrtf(var + EPS);
        sc[t] = s;
        sh[t] = beta[t] - mean * s;
    }
    __syncthreads();
    size_t total4 = (size_t)N * 16;
    for (size_t i = (size_t)blockIdx.x * blockDim.x + t; i < total4;
         i += (size_t)gridDim.x * blockDim.x) {
        float4 v = ((const float4*)buf)[i];
        int c0 = ((int)(i & 15)) << 2;
        v.x = v.x * sc[c0]     + sh[c0];
        v.y = v.y * sc[c0 + 1] + sh[c0 + 1];
        v.z = v.z * sc[c0 + 2] + sh[c0 + 2];
        v.w = v.w * sc[c0 + 3] + sh[c0 + 3];
        ((float4*)buf)[i] = v;
    }
}

// fp32 -> bf16 elementwise convert (x_feats).
__global__ __launch_bounds__(256)
void cvt_bf16(const float* __restrict__ in, unsigned short* __restrict__ out,
              size_t n4)
{
    for (size_t i = (size_t)blockIdx.x * blockDim.x + threadIdx.x; i < n4;
         i += (size_t)gridDim.x * blockDim.x) {
        float4 v = ((const float4*)in)[i];
        ushort4 o;
        o.x = f2bf(v.x); o.y = f2bf(v.y); o.z = f2bf(v.z); o.w = f2bf(v.w);
        ((ushort4*)out)[i] = o;
    }
}

// Zero the sentinel rows (index tableN) of all gatherable feature tables.
__global__ __launch_bounds__(256)
void zero_sentinels(unsigned short* xb, int Nin128,
                    unsigned short* tb, int Nin64,
                    unsigned short* ub, unsigned short* ab, unsigned short* vb,
                    int Nout64)
{
    int t = threadIdx.x;
    if (t < 128) xb[(size_t)Nin128 + t] = 0;
    if (t < 64) {
        tb[(size_t)Nin64 + t] = 0;
        ub[(size_t)Nout64 + t] = 0;
        ab[(size_t)Nout64 + t] = 0;
        vb[(size_t)Nout64 + t] = 0;
    }
}

// Permute W[k][c][d] fp32 -> Wt2 bf16 with per-lane fragment layout:
// dst flat [kk][kc][ct][lane][8]; kk = k*NCH+cc; c = cc*64+kc*32+q*8+j; d = ct*16+m.
static __device__ __forceinline__ void wt2_one(int e, const float* __restrict__ W,
                                               unsigned short* __restrict__ Wt2,
                                               int NCH)
{
    int j  = e & 7;
    int l  = (e >> 3) & 63;
    int ct = (e >> 9) & 3;
    int kc = (e >> 11) & 1;
    int kk = e >> 12;
    int qq = l >> 4, mm = l & 15;
    int k  = kk / NCH, cc = kk % NCH;
    int Cin = NCH * 64;
    int c  = cc * 64 + kc * 32 + qq * 8 + j;
    int d  = ct * 16 + mm;
    Wt2[e] = f2bf(W[((size_t)k * Cin + c) * 64 + d]);
}

__global__ __launch_bounds__(256)
void wt_cvt_all(const float* __restrict__ W_trans, const float* __restrict__ W_up,
                const float* __restrict__ W1, const float* __restrict__ W2,
                const float* __restrict__ W3,
                unsigned short* __restrict__ wt_t, unsigned short* __restrict__ wt_u,
                unsigned short* __restrict__ wt1, unsigned short* __restrict__ wt2,
                unsigned short* __restrict__ wt3)
{
    const int S0 = 27 * 128 * 64;            // trans (KT=54)
    const int S1 = 27 * 64 * 64;             // up
    const int S2 = 9 * 64 * 64;              // W1
    const int S3 = 9 * 64 * 64;              // W2
    const int S4 = 27 * 64 * 64;             // W3
    int e = blockIdx.x * blockDim.x + threadIdx.x;
    if (e < S0) { wt2_one(e, W_trans, wt_t, 2); return; }
    e -= S0;
    if (e < S1) { wt2_one(e, W_up, wt_u, 1); return; }
    e -= S1;
    if (e < S2) { wt2_one(e, W1, wt1, 1); return; }
    e -= S2;
    if (e < S3) { wt2_one(e, W2, wt2, 1); return; }
    e -= S3;
    if (e < S4) { wt2_one(e, W3, wt3, 1); }
}

extern "C" void kernel_launch(void* const* d_in, const int* in_sizes, int n_in,
                              void* d_out, int out_size, void* d_ws, size_t ws_size,
                              hipStream_t stream) {
    const float* x_feats   = (const float*)d_in[0];
    const float* skip      = (const float*)d_in[1];
    const int*   nbr_trans = (const int*)d_in[2];
    const int*   nbr_up    = (const int*)d_in[3];
    const int*   nbr1      = (const int*)d_in[4];
    const int*   nbr2      = (const int*)d_in[5];
    const int*   nbr3      = (const int*)d_in[6];
    const float* W_trans   = (const float*)d_in[7];
    const float* W_up      = (const float*)d_in[8];
    const float* W1        = (const float*)d_in[9];
    const float* W2        = (const float*)d_in[10];
    const float* W3        = (const float*)d_in[11];
    const float* gamma_t   = (const float*)d_in[12];
    const float* beta_t    = (const float*)d_in[13];
    const float* gamma1    = (const float*)d_in[14];
    const float* beta1     = (const float*)d_in[15];
    const float* gamma2    = (const float*)d_in[16];
    const float* beta2     = (const float*)d_in[17];
    const float* gamma3    = (const float*)d_in[18];
    const float* beta3     = (const float*)d_in[19];

    const int Nin  = in_sizes[0] / 128;   // 80000
    const int Nout = in_sizes[1] / 64;    // 200000

    size_t off = 0;
    auto alloc = [&](size_t bytes) {
        void* p = (char*)d_ws + off;
        off = (off + bytes + 255) & ~(size_t)255;
        return p;
    };
    unsigned short* xb   = (unsigned short*)alloc(((size_t)Nin + 1) * 128 * 2);
    unsigned short* tb   = (unsigned short*)alloc(((size_t)Nin + 1) * 64 * 2);
    unsigned short* ub   = (unsigned short*)alloc(((size_t)Nout + 1) * 64 * 2);
    unsigned short* ab   = (unsigned short*)alloc(((size_t)Nout + 1) * 64 * 2);
    unsigned short* vb   = (unsigned short*)alloc(((size_t)Nout + 1) * 64 * 2);
    unsigned short* wt_t = (unsigned short*)alloc((size_t)27 * 128 * 64 * 2);
    unsigned short* wt_u = (unsigned short*)alloc((size_t)27 * 64 * 64 * 2);
    unsigned short* wt1  = (unsigned short*)alloc((size_t)9 * 64 * 64 * 2);
    unsigned short* wt2  = (unsigned short*)alloc((size_t)9 * 64 * 64 * 2);
    unsigned short* wt3  = (unsigned short*)alloc((size_t)27 * 64 * 64 * 2);
    float* stats = (float*)alloc(512 * sizeof(float));
    float* out   = (float*)d_out;

    hipMemsetAsync(stats, 0, 512 * sizeof(float), stream);

    dim3 blk(256);
    const float invNin  = 1.f / (float)Nin;
    const float invNout = 1.f / (float)Nout;

    wt_cvt_all<<<2016, blk, 0, stream>>>(W_trans, W_up, W1, W2, W3,
                                         wt_t, wt_u, wt1, wt2, wt3);
    cvt_bf16<<<2048, blk, 0, stream>>>(x_feats, xb, (size_t)Nin * 32);
    zero_sentinels<<<1, blk, 0, stream>>>(xb, Nin * 128, tb, Nin * 64,
                                          ub, ab, vb, Nout * 64);

    const int gIn  = (Nin  + 127) / 128;  // 625
    const int gOut = (Nout + 127) / 128;  // 1563

    // trans_dilao: Cin=128, K=27 + LeakyReLU + BN
    conv_mfma<27, 2><<<gIn, blk, 0, stream>>>(xb, Nin, nbr_trans, Nin,
                                              wt_t, nullptr, tb, nullptr, stats + 0, 1);
    bn_apply_bf16<<<1024, blk, 0, stream>>>(tb, (size_t)Nin * 8, stats + 0,
                                            gamma_t, beta_t, invNin);
    // SparseInverseConv K=27 + skip (no act/bn)
    conv_mfma<27, 1><<<gOut, blk, 0, stream>>>(tb, Nin, nbr_up, Nout,
                                               wt_u, skip, ub, nullptr, nullptr, 0);
    // conv1 K=9 + LeakyReLU + BN
    conv_mfma<9, 1><<<gOut, blk, 0, stream>>>(ub, Nout, nbr1, Nout,
                                              wt1, nullptr, ab, nullptr, stats + 128, 1);
    bn_apply_bf16<<<2048, blk, 0, stream>>>(ab, (size_t)Nout * 8, stats + 128,
                                            gamma1, beta1, invNout);
    // conv2 K=9 + LeakyReLU + BN
    conv_mfma<9, 1><<<gOut, blk, 0, stream>>>(ab, Nout, nbr2, Nout,
                                              wt2, nullptr, vb, nullptr, stats + 256, 1);
    bn_apply_bf16<<<2048, blk, 0, stream>>>(vb, (size_t)Nout * 8, stats + 256,
                                            gamma2, beta2, invNout);
    // conv3 K=27 + LeakyReLU + BN -> d_out (fp32), normalize in place
    conv_mfma<27, 1><<<gOut, blk, 0, stream>>>(vb, Nout, nbr3, Nout,
                                               wt3, nullptr, nullptr, out, stats + 384, 1);
    bn_apply_f32<<<2048, blk, 0, stream>>>(out, Nout, stats + 384,
                                           gamma3, beta3, invNout);
}